// Round 3
// baseline (588.831 us; speedup 1.0000x reference)
//
#include <hip/hip_runtime.h>
#include <hip/hip_bf16.h>
#include <math.h>

// N=64, C_IN=C_OUT=64, T=300, V=25, INTER_C=16, NUM_SUBSET=3
// v7: wave-local restructure (de-risked v6). Block = 256 threads (4 waves),
// each wave owns ONE t-value (25 cols). Per subset, per wave:
//   PQ-GEMM -> private LDS scratch (same-wave RAW, lgkmcnt only)
//   S-GEMM + in-register softmax (sval ends lane-aligned for Phase C)
//   Z-GEMM 32x32x16 + fold into R.
// ONE __syncthreads per block (after X staging).
// LDS 24.9 KB -> 6 blocks/CU = 24 waves/CU. launch_bounds(256,6) -> VGPR<=85.

typedef __attribute__((ext_vector_type(8)))  short bf8;
typedef __attribute__((ext_vector_type(4)))  short bf4;
typedef __attribute__((ext_vector_type(4)))  float f4;
typedef __attribute__((ext_vector_type(16))) float f16v;

#define TT    4
#define COLS  100   // 4 t * 25 v, all real (no pad cols)
#define XROW  72    // shorts per Xb row (mult of 8 -> 16B-aligned bf8 reads)
#define PQROW 40    // shorts per PQ scratch row (P 0:16, Q 16:32, pad)

// workspace layout (bytes)
#define WS_AW    0        // [3][16][64] bf16 = 6144
#define WS_BW    6144     // [3][16][64] bf16 = 6144
#define WS_GW    12288    // [3][64][64] bf16 = 24576
#define WS_COLA  36864    // [75] f32 (pad to 512)
#define WS_SCL   37376    // [64] f32
#define WS_SHF   37632    // [64] f32
#define WS_END   37888

__device__ __forceinline__ short f2bf(float f) {
  __hip_bfloat16 h = __float2bfloat16(f);
  return __builtin_bit_cast(short, h);
}
__device__ __forceinline__ float bf2f(short s) {
  union { unsigned u; float f; } v;
  v.u = ((unsigned)(unsigned short)s) << 16;
  return v.f;
}
__device__ __forceinline__ float rsum16(float v) {
  v += __shfl_xor(v, 1);
  v += __shfl_xor(v, 2);
  v += __shfl_xor(v, 4);
  v += __shfl_xor(v, 8);
  return v;
}

// ---------------- prep: weights->bf16, colA, fused BN scale/shift ----------------
__global__ void tagc_prep(
    const float* __restrict__ A,    const float* __restrict__ G,
    const float* __restrict__ g_w,  const float* __restrict__ g_b,
    const float* __restrict__ a_w,  const float* __restrict__ b_w,
    const float* __restrict__ bn_g, const float* __restrict__ bn_b,
    const float* __restrict__ bn_m, const float* __restrict__ bn_v,
    short* __restrict__ aw_bf, short* __restrict__ bw_bf,
    short* __restrict__ gw_bf, float* __restrict__ colA3,
    float* __restrict__ scl,   float* __restrict__ shf2)
{
  const int b = blockIdx.x, tid = threadIdx.x;
  if (b < 12) {                       // g_w: 12288 elems, 1024/block
    int base = b * 1024 + tid * 4;
    f4 v = *(const f4*)(g_w + base);
    bf4 o;
    #pragma unroll
    for (int r = 0; r < 4; ++r) o[r] = f2bf(v[r]);
    *(bf4*)(gw_bf + base) = o;
  } else if (b == 12) {               // a_w: 3072 elems
    #pragma unroll
    for (int g = 0; g < 3; ++g) {
      int base = g * 1024 + tid * 4;
      f4 v = *(const f4*)(a_w + base);
      bf4 o;
      #pragma unroll
      for (int r = 0; r < 4; ++r) o[r] = f2bf(v[r]);
      *(bf4*)(aw_bf + base) = o;
    }
  } else if (b == 13) {               // b_w: 3072 elems
    #pragma unroll
    for (int g = 0; g < 3; ++g) {
      int base = g * 1024 + tid * 4;
      f4 v = *(const f4*)(b_w + base);
      bf4 o;
      #pragma unroll
      for (int r = 0; r < 4; ++r) o[r] = f2bf(v[r]);
      *(bf4*)(bw_bf + base) = o;
    }
  } else if (b == 14) {               // colA[i][v] = sum_a (A+G)[i][a][v]
    if (tid < 75) {
      int i = tid / 25, v = tid - 25 * i;
      float s = 0.f;
      for (int a = 0; a < 25; ++a)
        s += A[i * 625 + a * 25 + v] + G[i * 625 + a * 25 + v];
      colA3[tid] = s;
    }
  } else {                            // fused BN: scl, shf2 = bb - bm*scl + (sum g_b)*scl
    if (tid < 64) {
      float sc  = bn_g[tid] * rsqrtf(bn_v[tid] + 1e-5f);
      float gbs = g_b[tid] + g_b[64 + tid] + g_b[128 + tid];
      scl[tid]  = sc;
      shf2[tid] = bn_b[tid] - bn_m[tid] * sc + gbs * sc;
    }
  }
}

// ---------------- main ----------------
__launch_bounds__(256, 6)
__global__ void tagc_v7_kernel(
    const float* __restrict__ x,      // [64,64,300,25]
    const float* __restrict__ a_b,    // [3,16]
    const float* __restrict__ b_b,    // [3,16]
    const short* __restrict__ aw_bf,  // [3,16,64] bf16
    const short* __restrict__ bw_bf,  // [3,16,64] bf16
    const short* __restrict__ gw_bf,  // [3,64,64] bf16
    const float* __restrict__ colA3,  // [75]
    const float* __restrict__ sclp,   // [64]
    const float* __restrict__ shf2p,  // [64]
    float* __restrict__ out)
{
  __shared__ __align__(16) short Xb[COLS * XROW];         // [col][c] bf16 (100 rows)
  __shared__ __align__(16) short PQs[TT * 32 * PQROW];    // per-wave scratch
  __shared__ float colA[75];

  const int tid  = threadIdx.x;
  const int wave = tid >> 6;          // 0..3 == local t index
  const int lane = tid & 63;
  const int l15  = lane & 15;
  const int quad = lane >> 4;
  const int l31  = lane & 31;
  const int hl   = lane >> 5;

  // XCD-bijective remap (4800 blocks % 8 == 0): all 75 t-chunks of one n stay
  // on one XCD's L2 (t-neighbor blocks share output cache lines -> local RMW).
  const int lin = blockIdx.y * 75 + blockIdx.x;
  const int idx = lin >> 3;
  const int n   = ((lin & 7) << 3) + idx / 75;
  const int t0  = (idx % 75) * TT;

  if (tid < 75) colA[tid] = colA3[tid];

  // stage X -> Xb (bf16, [col][c]); 16 c4-groups x 100 cols = 1600 items
  {
    const float* xb = x + (long)n * 480000 + t0 * 25;
    #pragma unroll
    for (int k = 0; k < 7; ++k) {
      int idxs = k * 256 + tid;
      if (idxs < 1600) {
        int c4  = idxs / 100;           // 0..15
        int col = idxs - 100 * c4;      // 0..99
        bf4 wv;
        #pragma unroll
        for (int j = 0; j < 4; ++j)
          wv[j] = f2bf(xb[(4 * c4 + j) * 7500 + col]);
        *(bf4*)&Xb[col * XROW + 4 * c4] = wv;
      }
    }
  }

  f16v R0, R1;
  #pragma unroll
  for (int r = 0; r < 16; ++r) { R0[r] = 0.f; R1[r] = 0.f; }

  __syncthreads();   // the ONLY barrier

  const int w25 = wave * 25;
  short* PQw = PQs + wave * (32 * PQROW);
  const bf8 Z8 = {0,0,0,0,0,0,0,0};

  for (int i = 0; i < 3; ++i) {
    // ===== Phase A (wave-local): P,Q for this wave's 25 cols, 16x16x32 =====
    #pragma unroll
    for (int mt = 0; mt < 2; ++mt) {
      const short* Wb = (mt ? bw_bf : aw_bf) + i * 1024;
      const float* Bv = (mt ? b_b : a_b) + i * 16;
      bf8 W0 = *(const bf8*)(Wb + l15 * 64 + quad * 8);
      bf8 W1 = *(const bf8*)(Wb + l15 * 64 + 32 + quad * 8);
      float b0 = Bv[quad * 4 + 0], b1 = Bv[quad * 4 + 1];
      float b2 = Bv[quad * 4 + 2], b3 = Bv[quad * 4 + 3];
      #pragma unroll
      for (int ct = 0; ct < 2; ++ct) {
        bf8 B0 = Z8, B1 = Z8;
        if (ct == 0 || l15 < 9) {       // row <= w25+24 <= 99, in-bounds
          int row = w25 + ct * 16 + l15;
          B0 = *(const bf8*)&Xb[row * XROW + quad * 8];
          B1 = *(const bf8*)&Xb[row * XROW + 32 + quad * 8];
        }
        f4 acc = {0.f, 0.f, 0.f, 0.f};
        acc = __builtin_amdgcn_mfma_f32_16x16x32_bf16(W0, B0, acc, 0, 0, 0);
        acc = __builtin_amdgcn_mfma_f32_16x16x32_bf16(W1, B1, acc, 0, 0, 0);
        bf4 pw;
        pw[0] = f2bf(acc[0] + b0); pw[1] = f2bf(acc[1] + b1);
        pw[2] = f2bf(acc[2] + b2); pw[3] = f2bf(acc[3] + b3);
        *(bf4*)&PQw[(ct * 16 + l15) * PQROW + mt * 16 + quad * 4] = pw;
      }
    }
    // same-wave RAW on PQw: compiler inserts lgkmcnt wait; no barrier needed.

    // ===== Phase B (wave-local): S-GEMM + in-register softmax =====
    f4 sacc[2][2];
    #pragma unroll
    for (int am = 0; am < 2; ++am) {
      bf8 Afr = Z8;
      if (quad < 2 && (am * 16 + l15) < 25)
        Afr = *(const bf8*)&PQw[(am * 16 + l15) * PQROW + quad * 8];
      #pragma unroll
      for (int wm = 0; wm < 2; ++wm) {
        bf8 Bfr = Z8;
        if (quad < 2 && (wm * 16 + l15) < 25)
          Bfr = *(const bf8*)&PQw[(wm * 16 + l15) * PQROW + 16 + quad * 8];
        f4 z = {0.f, 0.f, 0.f, 0.f};
        sacc[am][wm] = __builtin_amdgcn_mfma_f32_16x16x32_bf16(Afr, Bfr, z, 0, 0, 0);
      }
    }
    const bool w1ok = (l15 < 9);
    float cs0 = 0.f, cs1 = 0.f;
    #pragma unroll
    for (int am = 0; am < 2; ++am) {
      #pragma unroll
      for (int r = 0; r < 4; ++r) {
        float e0 = __expf(sacc[am][0][r] * 0.0625f);
        float e1 = w1ok ? __expf(sacc[am][1][r] * 0.0625f) : 0.f;
        float d  = rsum16(e0 + e1);
        float rd = 1.f / d;
        int a = am * 16 + quad * 4 + r;
        if (a < 25) { cs0 += e0 * rd; cs1 += e1 * rd; }
      }
    }
    cs0 += __shfl_xor(cs0, 16); cs0 += __shfl_xor(cs0, 32);
    cs1 += __shfl_xor(cs1, 16); cs1 += __shfl_xor(cs1, 32);
    // sval is lane-aligned for Phase C: col = w25 + l31 -> v = l31
    float sval = 0.f;
    if (l31 < 25) {
      float csel = (l31 < 16) ? cs0 : cs1;
      sval = csel + colA[i * 25 + l31];
    }

    // ===== Phase C (wave-local): Z-GEMM 32x32x16 + fold into R =====
    #pragma unroll
    for (int tr = 0; tr < 2; ++tr) {
      f16v za;
      #pragma unroll
      for (int r = 0; r < 16; ++r) za[r] = 0.f;
      #pragma unroll
      for (int kk = 0; kk < 4; ++kk) {
        bf8 Bf = Z8;
        if (l31 < 25)
          Bf = *(const bf8*)&Xb[(w25 + l31) * XROW + kk * 16 + hl * 8];
        bf8 Ag = *(const bf8*)(gw_bf + i * 4096 + (tr * 32 + l31) * 64 + kk * 16 + hl * 8);
        za = __builtin_amdgcn_mfma_f32_32x32x16_bf16(Ag, Bf, za, 0, 0, 0);
      }
      if (tr == 0) {
        #pragma unroll
        for (int r = 0; r < 16; ++r) R0[r] += za[r] * sval;
      } else {
        #pragma unroll
        for (int r = 0; r < 16; ++r) R1[r] += za[r] * sval;
      }
    }
  }

  // ===== epilogue (wave-local): fused scale/shift + residual + ReLU =====
  if (l31 < 25) {
    const int col = w25 + l31;
    float* obase = out + (long)n * 480000 + t0 * 25 + col;
    #pragma unroll
    for (int tr = 0; tr < 2; ++tr) {
      #pragma unroll
      for (int rg = 0; rg < 4; ++rg) {
        int ob = tr * 32 + rg * 8 + hl * 4;   // 4 contiguous o
        f4 sc = *(const f4*)(sclp + ob);
        f4 sh = *(const f4*)(shf2p + ob);
        bf4 res = *(const bf4*)&Xb[col * XROW + ob];
        #pragma unroll
        for (int r = 0; r < 4; ++r) {
          float acc = tr ? R1[rg * 4 + r] : R0[rg * 4 + r];
          float h = acc * sc[r] + sh[r] + bf2f(res[r]);
          obase[(long)(ob + r) * 7500] = fmaxf(h, 0.f);
        }
      }
    }
  }
}

extern "C" void kernel_launch(void* const* d_in, const int* in_sizes, int n_in,
                              void* d_out, int out_size, void* d_ws, size_t ws_size,
                              hipStream_t stream) {
  (void)in_sizes; (void)n_in; (void)ws_size; (void)out_size;
  char* ws = (char*)d_ws;
  short* aw_bf = (short*)(ws + WS_AW);
  short* bw_bf = (short*)(ws + WS_BW);
  short* gw_bf = (short*)(ws + WS_GW);
  float* colA3 = (float*)(ws + WS_COLA);
  float* scl   = (float*)(ws + WS_SCL);
  float* shf2  = (float*)(ws + WS_SHF);

  tagc_prep<<<dim3(16), dim3(256), 0, stream>>>(
      (const float*)d_in[1],  (const float*)d_in[2],   // A, graph_attn
      (const float*)d_in[3],  (const float*)d_in[4],   // g_w, g_b
      (const float*)d_in[5],  (const float*)d_in[7],   // a_w, b_w
      (const float*)d_in[9],  (const float*)d_in[10],  // bn_gamma, bn_beta
      (const float*)d_in[11], (const float*)d_in[12],  // bn_mean, bn_var
      aw_bf, bw_bf, gw_bf, colA3, scl, shf2);

  dim3 grid(300 / TT, 64);   // 75 x 64
  tagc_v7_kernel<<<grid, dim3(256), 0, stream>>>(
      (const float*)d_in[0],                           // x
      (const float*)d_in[6],  (const float*)d_in[8],   // a_b, b_b
      aw_bf, bw_bf, gw_bf, colA3, scl, shf2,
      (float*)d_out);
}

// Round 4
// 564.064 us; speedup vs baseline: 1.0439x; 1.0439x over previous
//
#include <hip/hip_runtime.h>
#include <hip/hip_bf16.h>
#include <math.h>

// N=64, C_IN=C_OUT=64, T=300, V=25, INTER_C=16, NUM_SUBSET=3
// v8 = v7 wave-local compute + traffic-fixed epilogue.
// Block = 256 threads (4 waves), each wave owns ONE t-value (25 cols).
// Compute (per subset, per wave, barrier-free): PQ-GEMM -> private LDS
// scratch -> S-GEMM + in-register softmax -> Z-GEMM 32x32x16 + fold.
// Epilogue: fold BN/residual/ReLU in regs, stage into LDS [64][104] f32
// (aliased over Xb/PQs/colA), then block-coordinated float4 stores writing
// whole 400B row-spans (v7's 100B scattered partial-line stores caused 5x
// RMW write amplification -> 1.09GB HBM traffic -> 430us).
// 3 barriers/block. LDS 26.6KB -> 6 blocks/CU.

typedef __attribute__((ext_vector_type(8)))  short bf8;
typedef __attribute__((ext_vector_type(4)))  short bf4;
typedef __attribute__((ext_vector_type(4)))  float f4;
typedef __attribute__((ext_vector_type(16))) float f16v;

#define TT     4
#define COLS   100   // 4 t * 25 v, all real
#define XROW   72    // shorts per Xb row
#define PQROW  40    // shorts per PQ scratch row (P 0:16, Q 16:32, pad)
#define OUTROW 104   // f32 per out-stage row (100 padded to 104)

// smem layout (bytes) -- OutS aliases Xb/PQs/colA (dead by epilogue stage 2)
#define SM_XB    0       // short[100*72]  = 14400
#define SM_PQ    14400   // short[4*32*40] = 10240 -> 24640
#define SM_COLA  24640   // float[75]      = 300   -> 24940
#define SM_SIZE  26624   // max(24940, 64*104*4 = 26624)

// workspace layout (bytes)
#define WS_AW    0        // [3][16][64] bf16 = 6144
#define WS_BW    6144     // [3][16][64] bf16 = 6144
#define WS_GW    12288    // [3][64][64] bf16 = 24576
#define WS_COLA  36864    // [75] f32 (pad to 512)
#define WS_SCL   37376    // [64] f32
#define WS_SHF   37632    // [64] f32
#define WS_END   37888

__device__ __forceinline__ short f2bf(float f) {
  __hip_bfloat16 h = __float2bfloat16(f);
  return __builtin_bit_cast(short, h);
}
__device__ __forceinline__ float bf2f(short s) {
  union { unsigned u; float f; } v;
  v.u = ((unsigned)(unsigned short)s) << 16;
  return v.f;
}
__device__ __forceinline__ float rsum16(float v) {
  v += __shfl_xor(v, 1);
  v += __shfl_xor(v, 2);
  v += __shfl_xor(v, 4);
  v += __shfl_xor(v, 8);
  return v;
}

// ---------------- prep: weights->bf16, colA, fused BN scale/shift ----------------
__global__ void tagc_prep(
    const float* __restrict__ A,    const float* __restrict__ G,
    const float* __restrict__ g_w,  const float* __restrict__ g_b,
    const float* __restrict__ a_w,  const float* __restrict__ b_w,
    const float* __restrict__ bn_g, const float* __restrict__ bn_b,
    const float* __restrict__ bn_m, const float* __restrict__ bn_v,
    short* __restrict__ aw_bf, short* __restrict__ bw_bf,
    short* __restrict__ gw_bf, float* __restrict__ colA3,
    float* __restrict__ scl,   float* __restrict__ shf2)
{
  const int b = blockIdx.x, tid = threadIdx.x;
  if (b < 12) {                       // g_w: 12288 elems, 1024/block
    int base = b * 1024 + tid * 4;
    f4 v = *(const f4*)(g_w + base);
    bf4 o;
    #pragma unroll
    for (int r = 0; r < 4; ++r) o[r] = f2bf(v[r]);
    *(bf4*)(gw_bf + base) = o;
  } else if (b == 12) {               // a_w: 3072 elems
    #pragma unroll
    for (int g = 0; g < 3; ++g) {
      int base = g * 1024 + tid * 4;
      f4 v = *(const f4*)(a_w + base);
      bf4 o;
      #pragma unroll
      for (int r = 0; r < 4; ++r) o[r] = f2bf(v[r]);
      *(bf4*)(aw_bf + base) = o;
    }
  } else if (b == 13) {               // b_w: 3072 elems
    #pragma unroll
    for (int g = 0; g < 3; ++g) {
      int base = g * 1024 + tid * 4;
      f4 v = *(const f4*)(b_w + base);
      bf4 o;
      #pragma unroll
      for (int r = 0; r < 4; ++r) o[r] = f2bf(v[r]);
      *(bf4*)(bw_bf + base) = o;
    }
  } else if (b == 14) {               // colA[i][v] = sum_a (A+G)[i][a][v]
    if (tid < 75) {
      int i = tid / 25, v = tid - 25 * i;
      float s = 0.f;
      for (int a = 0; a < 25; ++a)
        s += A[i * 625 + a * 25 + v] + G[i * 625 + a * 25 + v];
      colA3[tid] = s;
    }
  } else {                            // fused BN: scl, shf2 = bb - bm*scl + (sum g_b)*scl
    if (tid < 64) {
      float sc  = bn_g[tid] * rsqrtf(bn_v[tid] + 1e-5f);
      float gbs = g_b[tid] + g_b[64 + tid] + g_b[128 + tid];
      scl[tid]  = sc;
      shf2[tid] = bn_b[tid] - bn_m[tid] * sc + gbs * sc;
    }
  }
}

// ---------------- main ----------------
__launch_bounds__(256, 6)
__global__ void tagc_v8_kernel(
    const float* __restrict__ x,      // [64,64,300,25]
    const float* __restrict__ a_b,    // [3,16]
    const float* __restrict__ b_b,    // [3,16]
    const short* __restrict__ aw_bf,  // [3,16,64] bf16
    const short* __restrict__ bw_bf,  // [3,16,64] bf16
    const short* __restrict__ gw_bf,  // [3,64,64] bf16
    const float* __restrict__ colA3,  // [75]
    const float* __restrict__ sclp,   // [64]
    const float* __restrict__ shf2p,  // [64]
    float* __restrict__ out)
{
  __shared__ __align__(16) char smem[SM_SIZE];
  short* Xb   = (short*)(smem + SM_XB);    // [col][c] bf16
  short* PQs  = (short*)(smem + SM_PQ);    // per-wave scratch
  float* colA = (float*)(smem + SM_COLA);  // [75]
  float* OutS = (float*)smem;              // [64 o][104 col] f32 (epilogue alias)

  const int tid  = threadIdx.x;
  const int wave = tid >> 6;          // 0..3 == local t index
  const int lane = tid & 63;
  const int l15  = lane & 15;
  const int quad = lane >> 4;
  const int l31  = lane & 31;
  const int hl   = lane >> 5;

  // XCD-bijective remap (4800 blocks % 8 == 0): all 75 t-chunks of one n stay
  // on one XCD's L2 (t-neighbor blocks share boundary cache lines).
  const int lin = blockIdx.y * 75 + blockIdx.x;
  const int idx = lin >> 3;
  const int n   = ((lin & 7) << 3) + idx / 75;
  const int t0  = (idx % 75) * TT;

  if (tid < 75) colA[tid] = colA3[tid];

  // stage X -> Xb (bf16, [col][c]); 16 c4-groups x 100 cols = 1600 items
  {
    const float* xb = x + (long)n * 480000 + t0 * 25;
    #pragma unroll
    for (int k = 0; k < 7; ++k) {
      int idxs = k * 256 + tid;
      if (idxs < 1600) {
        int c4  = idxs / 100;           // 0..15
        int col = idxs - 100 * c4;      // 0..99
        bf4 wv;
        #pragma unroll
        for (int j = 0; j < 4; ++j)
          wv[j] = f2bf(xb[(4 * c4 + j) * 7500 + col]);
        *(bf4*)&Xb[col * XROW + 4 * c4] = wv;
      }
    }
  }

  f16v R0, R1;
  #pragma unroll
  for (int r = 0; r < 16; ++r) { R0[r] = 0.f; R1[r] = 0.f; }

  __syncthreads();   // barrier 1: staging done

  const int w25 = wave * 25;
  short* PQw = PQs + wave * (32 * PQROW);
  const bf8 Z8 = {0,0,0,0,0,0,0,0};

  for (int i = 0; i < 3; ++i) {
    // ===== Phase A (wave-local): P,Q for this wave's 25 cols, 16x16x32 =====
    #pragma unroll
    for (int mt = 0; mt < 2; ++mt) {
      const short* Wb = (mt ? bw_bf : aw_bf) + i * 1024;
      const float* Bv = (mt ? b_b : a_b) + i * 16;
      bf8 W0 = *(const bf8*)(Wb + l15 * 64 + quad * 8);
      bf8 W1 = *(const bf8*)(Wb + l15 * 64 + 32 + quad * 8);
      float b0 = Bv[quad * 4 + 0], b1 = Bv[quad * 4 + 1];
      float b2 = Bv[quad * 4 + 2], b3 = Bv[quad * 4 + 3];
      #pragma unroll
      for (int ct = 0; ct < 2; ++ct) {
        bf8 B0 = Z8, B1 = Z8;
        if (ct == 0 || l15 < 9) {       // row <= w25+24 <= 99, in-bounds
          int row = w25 + ct * 16 + l15;
          B0 = *(const bf8*)&Xb[row * XROW + quad * 8];
          B1 = *(const bf8*)&Xb[row * XROW + 32 + quad * 8];
        }
        f4 acc = {0.f, 0.f, 0.f, 0.f};
        acc = __builtin_amdgcn_mfma_f32_16x16x32_bf16(W0, B0, acc, 0, 0, 0);
        acc = __builtin_amdgcn_mfma_f32_16x16x32_bf16(W1, B1, acc, 0, 0, 0);
        bf4 pw;
        pw[0] = f2bf(acc[0] + b0); pw[1] = f2bf(acc[1] + b1);
        pw[2] = f2bf(acc[2] + b2); pw[3] = f2bf(acc[3] + b3);
        *(bf4*)&PQw[(ct * 16 + l15) * PQROW + mt * 16 + quad * 4] = pw;
      }
    }
    // same-wave RAW on PQw: compiler inserts lgkmcnt wait; no barrier needed.

    // ===== Phase B (wave-local): S-GEMM + in-register softmax =====
    f4 sacc[2][2];
    #pragma unroll
    for (int am = 0; am < 2; ++am) {
      bf8 Afr = Z8;
      if (quad < 2 && (am * 16 + l15) < 25)
        Afr = *(const bf8*)&PQw[(am * 16 + l15) * PQROW + quad * 8];
      #pragma unroll
      for (int wm = 0; wm < 2; ++wm) {
        bf8 Bfr = Z8;
        if (quad < 2 && (wm * 16 + l15) < 25)
          Bfr = *(const bf8*)&PQw[(wm * 16 + l15) * PQROW + 16 + quad * 8];
        f4 z = {0.f, 0.f, 0.f, 0.f};
        sacc[am][wm] = __builtin_amdgcn_mfma_f32_16x16x32_bf16(Afr, Bfr, z, 0, 0, 0);
      }
    }
    const bool w1ok = (l15 < 9);
    float cs0 = 0.f, cs1 = 0.f;
    #pragma unroll
    for (int am = 0; am < 2; ++am) {
      #pragma unroll
      for (int r = 0; r < 4; ++r) {
        float e0 = __expf(sacc[am][0][r] * 0.0625f);
        float e1 = w1ok ? __expf(sacc[am][1][r] * 0.0625f) : 0.f;
        float d  = rsum16(e0 + e1);
        float rd = 1.f / d;
        int a = am * 16 + quad * 4 + r;
        if (a < 25) { cs0 += e0 * rd; cs1 += e1 * rd; }
      }
    }
    cs0 += __shfl_xor(cs0, 16); cs0 += __shfl_xor(cs0, 32);
    cs1 += __shfl_xor(cs1, 16); cs1 += __shfl_xor(cs1, 32);
    // sval is lane-aligned for Phase C: col = w25 + l31 -> v = l31
    float sval = 0.f;
    if (l31 < 25) {
      float csel = (l31 < 16) ? cs0 : cs1;
      sval = csel + colA[i * 25 + l31];
    }

    // ===== Phase C (wave-local): Z-GEMM 32x32x16 + fold into R =====
    #pragma unroll
    for (int tr = 0; tr < 2; ++tr) {
      f16v za;
      #pragma unroll
      for (int r = 0; r < 16; ++r) za[r] = 0.f;
      #pragma unroll
      for (int kk = 0; kk < 4; ++kk) {
        bf8 Bf = Z8;
        if (l31 < 25)
          Bf = *(const bf8*)&Xb[(w25 + l31) * XROW + kk * 16 + hl * 8];
        bf8 Ag = *(const bf8*)(gw_bf + i * 4096 + (tr * 32 + l31) * 64 + kk * 16 + hl * 8);
        za = __builtin_amdgcn_mfma_f32_32x32x16_bf16(Ag, Bf, za, 0, 0, 0);
      }
      if (tr == 0) {
        #pragma unroll
        for (int r = 0; r < 16; ++r) R0[r] += za[r] * sval;
      } else {
        #pragma unroll
        for (int r = 0; r < 16; ++r) R1[r] += za[r] * sval;
      }
    }
  }

  // ===== epilogue stage 1: fold scale/shift + residual + ReLU (Xb live) =====
  if (l31 < 25) {
    const int col = w25 + l31;
    #pragma unroll
    for (int tr = 0; tr < 2; ++tr) {
      #pragma unroll
      for (int rg = 0; rg < 4; ++rg) {
        int ob = tr * 32 + rg * 8 + hl * 4;
        f4 sc = *(const f4*)(sclp + ob);
        f4 sh = *(const f4*)(shf2p + ob);
        bf4 res = *(const bf4*)&Xb[col * XROW + ob];
        #pragma unroll
        for (int r = 0; r < 4; ++r) {
          float acc = tr ? R1[rg * 4 + r] : R0[rg * 4 + r];
          float hv = fmaxf(acc * sc[r] + sh[r] + bf2f(res[r]), 0.f);
          if (tr) R1[rg * 4 + r] = hv; else R0[rg * 4 + r] = hv;
        }
      }
    }
  }

  __syncthreads();   // barrier 2: all Xb/PQs/colA reads done; OutS may alias

  // ===== epilogue stage 2: transpose-stage h into OutS [o][col] =====
  if (l31 < 25) {
    const int col = w25 + l31;
    #pragma unroll
    for (int tr = 0; tr < 2; ++tr) {
      #pragma unroll
      for (int rg = 0; rg < 4; ++rg) {
        int ob = tr * 32 + rg * 8 + hl * 4;
        #pragma unroll
        for (int r = 0; r < 4; ++r)
          OutS[(ob + r) * OUTROW + col] = tr ? R1[rg * 4 + r] : R0[rg * 4 + r];
      }
    }
  }

  __syncthreads();   // barrier 3: OutS complete

  // ===== epilogue stage 3: coalesced f4 stores, 2 full 400B rows / instr =====
  {
    float* obase = out + (long)n * 480000 + t0 * 25;
    #pragma unroll
    for (int rr = 0; rr < 8; ++rr) {
      int row = wave * 16 + rr * 2 + hl;   // o in [0,64)
      if (l31 < 25) {
        f4 vv = *(const f4*)&OutS[row * OUTROW + 4 * l31];
        *(f4*)(obase + (long)row * 7500 + 4 * l31) = vv;
      }
    }
  }
}

extern "C" void kernel_launch(void* const* d_in, const int* in_sizes, int n_in,
                              void* d_out, int out_size, void* d_ws, size_t ws_size,
                              hipStream_t stream) {
  (void)in_sizes; (void)n_in; (void)ws_size; (void)out_size;
  char* ws = (char*)d_ws;
  short* aw_bf = (short*)(ws + WS_AW);
  short* bw_bf = (short*)(ws + WS_BW);
  short* gw_bf = (short*)(ws + WS_GW);
  float* colA3 = (float*)(ws + WS_COLA);
  float* scl   = (float*)(ws + WS_SCL);
  float* shf2  = (float*)(ws + WS_SHF);

  tagc_prep<<<dim3(16), dim3(256), 0, stream>>>(
      (const float*)d_in[1],  (const float*)d_in[2],   // A, graph_attn
      (const float*)d_in[3],  (const float*)d_in[4],   // g_w, g_b
      (const float*)d_in[5],  (const float*)d_in[7],   // a_w, b_w
      (const float*)d_in[9],  (const float*)d_in[10],  // bn_gamma, bn_beta
      (const float*)d_in[11], (const float*)d_in[12],  // bn_mean, bn_var
      aw_bf, bw_bf, gw_bf, colA3, scl, shf2);

  dim3 grid(300 / TT, 64);   // 75 x 64
  tagc_v8_kernel<<<grid, dim3(256), 0, stream>>>(
      (const float*)d_in[0],                           // x
      (const float*)d_in[6],  (const float*)d_in[8],   // a_b, b_b
      aw_bf, bw_bf, gw_bf, colA3, scl, shf2,
      (float*)d_out);
}

// Round 5
// 323.829 us; speedup vs baseline: 1.8183x; 1.7419x over previous
//
#include <hip/hip_runtime.h>
#include <hip/hip_bf16.h>
#include <math.h>

// N=64, C_IN=C_OUT=64, T=300, V=25, INTER_C=16, NUM_SUBSET=3
// v9 = v8 with the spill fix.
// Round-4 diagnosis: __launch_bounds__(256,6) capped VGPRs at 85 < ~100 live
// -> scratch spills -> ~780MB of scratch HBM traffic (WRITE 660MB invariant
// under epilogue rewrite; VGPR_Count=40 impossible for 32 live accumulators).
// Fix: (256,4) -> cap 128, plus Phase-B serialized over am to cut sacc
// liveness 16->8. Structure otherwise identical to v8:
//   4 waves x 1 t-value each; PQ-GEMM -> wave-private LDS -> S-GEMM +
//   in-register softmax -> Z-GEMM 32x32x16 + fold; staged coalesced epilogue.
// 3 barriers/block. LDS 26.6KB.

typedef __attribute__((ext_vector_type(8)))  short bf8;
typedef __attribute__((ext_vector_type(4)))  short bf4;
typedef __attribute__((ext_vector_type(4)))  float f4;
typedef __attribute__((ext_vector_type(16))) float f16v;

#define TT     4
#define COLS   100   // 4 t * 25 v, all real
#define XROW   72    // shorts per Xb row
#define PQROW  40    // shorts per PQ scratch row (P 0:16, Q 16:32, pad)
#define OUTROW 104   // f32 per out-stage row (100 padded to 104)

// smem layout (bytes) -- OutS aliases Xb/PQs/colA (dead by epilogue stage 2)
#define SM_XB    0       // short[100*72]  = 14400
#define SM_PQ    14400   // short[4*32*40] = 10240 -> 24640
#define SM_COLA  24640   // float[75]      = 300   -> 24940
#define SM_SIZE  26624   // max(24940, 64*104*4 = 26624)

// workspace layout (bytes)
#define WS_AW    0        // [3][16][64] bf16 = 6144
#define WS_BW    6144     // [3][16][64] bf16 = 6144
#define WS_GW    12288    // [3][64][64] bf16 = 24576
#define WS_COLA  36864    // [75] f32 (pad to 512)
#define WS_SCL   37376    // [64] f32
#define WS_SHF   37632    // [64] f32
#define WS_END   37888

__device__ __forceinline__ short f2bf(float f) {
  __hip_bfloat16 h = __float2bfloat16(f);
  return __builtin_bit_cast(short, h);
}
__device__ __forceinline__ float bf2f(short s) {
  union { unsigned u; float f; } v;
  v.u = ((unsigned)(unsigned short)s) << 16;
  return v.f;
}
__device__ __forceinline__ float rsum16(float v) {
  v += __shfl_xor(v, 1);
  v += __shfl_xor(v, 2);
  v += __shfl_xor(v, 4);
  v += __shfl_xor(v, 8);
  return v;
}

// ---------------- prep: weights->bf16, colA, fused BN scale/shift ----------------
__global__ void tagc_prep(
    const float* __restrict__ A,    const float* __restrict__ G,
    const float* __restrict__ g_w,  const float* __restrict__ g_b,
    const float* __restrict__ a_w,  const float* __restrict__ b_w,
    const float* __restrict__ bn_g, const float* __restrict__ bn_b,
    const float* __restrict__ bn_m, const float* __restrict__ bn_v,
    short* __restrict__ aw_bf, short* __restrict__ bw_bf,
    short* __restrict__ gw_bf, float* __restrict__ colA3,
    float* __restrict__ scl,   float* __restrict__ shf2)
{
  const int b = blockIdx.x, tid = threadIdx.x;
  if (b < 12) {                       // g_w: 12288 elems, 1024/block
    int base = b * 1024 + tid * 4;
    f4 v = *(const f4*)(g_w + base);
    bf4 o;
    #pragma unroll
    for (int r = 0; r < 4; ++r) o[r] = f2bf(v[r]);
    *(bf4*)(gw_bf + base) = o;
  } else if (b == 12) {               // a_w: 3072 elems
    #pragma unroll
    for (int g = 0; g < 3; ++g) {
      int base = g * 1024 + tid * 4;
      f4 v = *(const f4*)(a_w + base);
      bf4 o;
      #pragma unroll
      for (int r = 0; r < 4; ++r) o[r] = f2bf(v[r]);
      *(bf4*)(aw_bf + base) = o;
    }
  } else if (b == 13) {               // b_w: 3072 elems
    #pragma unroll
    for (int g = 0; g < 3; ++g) {
      int base = g * 1024 + tid * 4;
      f4 v = *(const f4*)(b_w + base);
      bf4 o;
      #pragma unroll
      for (int r = 0; r < 4; ++r) o[r] = f2bf(v[r]);
      *(bf4*)(bw_bf + base) = o;
    }
  } else if (b == 14) {               // colA[i][v] = sum_a (A+G)[i][a][v]
    if (tid < 75) {
      int i = tid / 25, v = tid - 25 * i;
      float s = 0.f;
      for (int a = 0; a < 25; ++a)
        s += A[i * 625 + a * 25 + v] + G[i * 625 + a * 25 + v];
      colA3[tid] = s;
    }
  } else {                            // fused BN: scl, shf2 = bb - bm*scl + (sum g_b)*scl
    if (tid < 64) {
      float sc  = bn_g[tid] * rsqrtf(bn_v[tid] + 1e-5f);
      float gbs = g_b[tid] + g_b[64 + tid] + g_b[128 + tid];
      scl[tid]  = sc;
      shf2[tid] = bn_b[tid] - bn_m[tid] * sc + gbs * sc;
    }
  }
}

// ---------------- main ----------------
__launch_bounds__(256, 4)
__global__ void tagc_v9_kernel(
    const float* __restrict__ x,      // [64,64,300,25]
    const float* __restrict__ a_b,    // [3,16]
    const float* __restrict__ b_b,    // [3,16]
    const short* __restrict__ aw_bf,  // [3,16,64] bf16
    const short* __restrict__ bw_bf,  // [3,16,64] bf16
    const short* __restrict__ gw_bf,  // [3,64,64] bf16
    const float* __restrict__ colA3,  // [75]
    const float* __restrict__ sclp,   // [64]
    const float* __restrict__ shf2p,  // [64]
    float* __restrict__ out)
{
  __shared__ __align__(16) char smem[SM_SIZE];
  short* Xb   = (short*)(smem + SM_XB);    // [col][c] bf16
  short* PQs  = (short*)(smem + SM_PQ);    // per-wave scratch
  float* colA = (float*)(smem + SM_COLA);  // [75]
  float* OutS = (float*)smem;              // [64 o][104 col] f32 (epilogue alias)

  const int tid  = threadIdx.x;
  const int wave = tid >> 6;          // 0..3 == local t index
  const int lane = tid & 63;
  const int l15  = lane & 15;
  const int quad = lane >> 4;
  const int l31  = lane & 31;
  const int hl   = lane >> 5;

  // XCD-bijective remap (4800 blocks % 8 == 0): all 75 t-chunks of one n stay
  // on one XCD's L2 (t-neighbor blocks share boundary cache lines).
  const int lin = blockIdx.y * 75 + blockIdx.x;
  const int idx = lin >> 3;
  const int n   = ((lin & 7) << 3) + idx / 75;
  const int t0  = (idx % 75) * TT;

  if (tid < 75) colA[tid] = colA3[tid];

  // stage X -> Xb (bf16, [col][c]); 16 c4-groups x 100 cols = 1600 items
  {
    const float* xb = x + (long)n * 480000 + t0 * 25;
    #pragma unroll
    for (int k = 0; k < 7; ++k) {
      int idxs = k * 256 + tid;
      if (idxs < 1600) {
        int c4  = idxs / 100;           // 0..15
        int col = idxs - 100 * c4;      // 0..99
        bf4 wv;
        #pragma unroll
        for (int j = 0; j < 4; ++j)
          wv[j] = f2bf(xb[(4 * c4 + j) * 7500 + col]);
        *(bf4*)&Xb[col * XROW + 4 * c4] = wv;
      }
    }
  }

  f16v R0, R1;
  #pragma unroll
  for (int r = 0; r < 16; ++r) { R0[r] = 0.f; R1[r] = 0.f; }

  __syncthreads();   // barrier 1: staging done

  const int w25 = wave * 25;
  short* PQw = PQs + wave * (32 * PQROW);
  const bf8 Z8 = {0,0,0,0,0,0,0,0};

  for (int i = 0; i < 3; ++i) {
    // ===== Phase A (wave-local): P,Q for this wave's 25 cols, 16x16x32 =====
    #pragma unroll
    for (int mt = 0; mt < 2; ++mt) {
      const short* Wb = (mt ? bw_bf : aw_bf) + i * 1024;
      const float* Bv = (mt ? b_b : a_b) + i * 16;
      bf8 W0 = *(const bf8*)(Wb + l15 * 64 + quad * 8);
      bf8 W1 = *(const bf8*)(Wb + l15 * 64 + 32 + quad * 8);
      float b0 = Bv[quad * 4 + 0], b1 = Bv[quad * 4 + 1];
      float b2 = Bv[quad * 4 + 2], b3 = Bv[quad * 4 + 3];
      #pragma unroll
      for (int ct = 0; ct < 2; ++ct) {
        bf8 B0 = Z8, B1 = Z8;
        if (ct == 0 || l15 < 9) {       // row <= w25+24 <= 99, in-bounds
          int row = w25 + ct * 16 + l15;
          B0 = *(const bf8*)&Xb[row * XROW + quad * 8];
          B1 = *(const bf8*)&Xb[row * XROW + 32 + quad * 8];
        }
        f4 acc = {0.f, 0.f, 0.f, 0.f};
        acc = __builtin_amdgcn_mfma_f32_16x16x32_bf16(W0, B0, acc, 0, 0, 0);
        acc = __builtin_amdgcn_mfma_f32_16x16x32_bf16(W1, B1, acc, 0, 0, 0);
        bf4 pw;
        pw[0] = f2bf(acc[0] + b0); pw[1] = f2bf(acc[1] + b1);
        pw[2] = f2bf(acc[2] + b2); pw[3] = f2bf(acc[3] + b3);
        *(bf4*)&PQw[(ct * 16 + l15) * PQROW + mt * 16 + quad * 4] = pw;
      }
    }
    // same-wave RAW on PQw: compiler inserts lgkmcnt wait; no barrier needed.

    // ===== Phase B (wave-local): S-GEMM + in-register softmax, serial am =====
    // Q fragments hoisted; process the two S row-tiles one at a time so only
    // 8 accumulator floats are live (register-pressure fix).
    bf8 Bq0 = Z8, Bq1 = Z8;
    if (quad < 2)
      Bq0 = *(const bf8*)&PQw[l15 * PQROW + 16 + quad * 8];
    if (quad < 2 && l15 < 9)
      Bq1 = *(const bf8*)&PQw[(16 + l15) * PQROW + 16 + quad * 8];
    const bool w1ok = (l15 < 9);
    float cs0 = 0.f, cs1 = 0.f;
    #pragma unroll
    for (int am = 0; am < 2; ++am) {
      bf8 Afr = Z8;
      if (quad < 2 && (am * 16 + l15) < 25)
        Afr = *(const bf8*)&PQw[(am * 16 + l15) * PQROW + quad * 8];
      f4 z0 = {0.f, 0.f, 0.f, 0.f};
      f4 z1 = {0.f, 0.f, 0.f, 0.f};
      z0 = __builtin_amdgcn_mfma_f32_16x16x32_bf16(Afr, Bq0, z0, 0, 0, 0);
      z1 = __builtin_amdgcn_mfma_f32_16x16x32_bf16(Afr, Bq1, z1, 0, 0, 0);
      #pragma unroll
      for (int r = 0; r < 4; ++r) {
        float e0 = __expf(z0[r] * 0.0625f);
        float e1 = w1ok ? __expf(z1[r] * 0.0625f) : 0.f;
        float d  = rsum16(e0 + e1);
        float rd = 1.f / d;
        int a = am * 16 + quad * 4 + r;
        if (a < 25) { cs0 += e0 * rd; cs1 += e1 * rd; }
      }
    }
    cs0 += __shfl_xor(cs0, 16); cs0 += __shfl_xor(cs0, 32);
    cs1 += __shfl_xor(cs1, 16); cs1 += __shfl_xor(cs1, 32);
    // sval is lane-aligned for Phase C: col = w25 + l31 -> v = l31
    float sval = 0.f;
    if (l31 < 25) {
      float csel = (l31 < 16) ? cs0 : cs1;
      sval = csel + colA[i * 25 + l31];
    }

    // ===== Phase C (wave-local): Z-GEMM 32x32x16 + fold into R =====
    #pragma unroll
    for (int tr = 0; tr < 2; ++tr) {
      f16v za;
      #pragma unroll
      for (int r = 0; r < 16; ++r) za[r] = 0.f;
      #pragma unroll
      for (int kk = 0; kk < 4; ++kk) {
        bf8 Bf = Z8;
        if (l31 < 25)
          Bf = *(const bf8*)&Xb[(w25 + l31) * XROW + kk * 16 + hl * 8];
        bf8 Ag = *(const bf8*)(gw_bf + i * 4096 + (tr * 32 + l31) * 64 + kk * 16 + hl * 8);
        za = __builtin_amdgcn_mfma_f32_32x32x16_bf16(Ag, Bf, za, 0, 0, 0);
      }
      if (tr == 0) {
        #pragma unroll
        for (int r = 0; r < 16; ++r) R0[r] += za[r] * sval;
      } else {
        #pragma unroll
        for (int r = 0; r < 16; ++r) R1[r] += za[r] * sval;
      }
    }
  }

  // ===== epilogue stage 1: fold scale/shift + residual + ReLU (Xb live) =====
  if (l31 < 25) {
    const int col = w25 + l31;
    #pragma unroll
    for (int tr = 0; tr < 2; ++tr) {
      #pragma unroll
      for (int rg = 0; rg < 4; ++rg) {
        int ob = tr * 32 + rg * 8 + hl * 4;
        f4 sc = *(const f4*)(sclp + ob);
        f4 sh = *(const f4*)(shf2p + ob);
        bf4 res = *(const bf4*)&Xb[col * XROW + ob];
        #pragma unroll
        for (int r = 0; r < 4; ++r) {
          float acc = tr ? R1[rg * 4 + r] : R0[rg * 4 + r];
          float hv = fmaxf(acc * sc[r] + sh[r] + bf2f(res[r]), 0.f);
          if (tr) R1[rg * 4 + r] = hv; else R0[rg * 4 + r] = hv;
        }
      }
    }
  }

  __syncthreads();   // barrier 2: all Xb/PQs/colA reads done; OutS may alias

  // ===== epilogue stage 2: transpose-stage h into OutS [o][col] =====
  if (l31 < 25) {
    const int col = w25 + l31;
    #pragma unroll
    for (int tr = 0; tr < 2; ++tr) {
      #pragma unroll
      for (int rg = 0; rg < 4; ++rg) {
        int ob = tr * 32 + rg * 8 + hl * 4;
        #pragma unroll
        for (int r = 0; r < 4; ++r)
          OutS[(ob + r) * OUTROW + col] = tr ? R1[rg * 4 + r] : R0[rg * 4 + r];
      }
    }
  }

  __syncthreads();   // barrier 3: OutS complete

  // ===== epilogue stage 3: coalesced f4 stores, 2 full 400B rows / instr =====
  {
    float* obase = out + (long)n * 480000 + t0 * 25;
    #pragma unroll
    for (int rr = 0; rr < 8; ++rr) {
      int row = wave * 16 + rr * 2 + hl;   // o in [0,64)
      if (l31 < 25) {
        f4 vv = *(const f4*)&OutS[row * OUTROW + 4 * l31];
        *(f4*)(obase + (long)row * 7500 + 4 * l31) = vv;
      }
    }
  }
}

extern "C" void kernel_launch(void* const* d_in, const int* in_sizes, int n_in,
                              void* d_out, int out_size, void* d_ws, size_t ws_size,
                              hipStream_t stream) {
  (void)in_sizes; (void)n_in; (void)ws_size; (void)out_size;
  char* ws = (char*)d_ws;
  short* aw_bf = (short*)(ws + WS_AW);
  short* bw_bf = (short*)(ws + WS_BW);
  short* gw_bf = (short*)(ws + WS_GW);
  float* colA3 = (float*)(ws + WS_COLA);
  float* scl   = (float*)(ws + WS_SCL);
  float* shf2  = (float*)(ws + WS_SHF);

  tagc_prep<<<dim3(16), dim3(256), 0, stream>>>(
      (const float*)d_in[1],  (const float*)d_in[2],   // A, graph_attn
      (const float*)d_in[3],  (const float*)d_in[4],   // g_w, g_b
      (const float*)d_in[5],  (const float*)d_in[7],   // a_w, b_w
      (const float*)d_in[9],  (const float*)d_in[10],  // bn_gamma, bn_beta
      (const float*)d_in[11], (const float*)d_in[12],  // bn_mean, bn_var
      aw_bf, bw_bf, gw_bf, colA3, scl, shf2);

  dim3 grid(300 / TT, 64);   // 75 x 64
  tagc_v9_kernel<<<grid, dim3(256), 0, stream>>>(
      (const float*)d_in[0],                           // x
      (const float*)d_in[6],  (const float*)d_in[8],   // a_b, b_b
      aw_bf, bw_bf, gw_bf, colA3, scl, shf2,
      (float*)d_out);
}